// Round 4
// baseline (521.316 us; speedup 1.0000x reference)
//
#include <hip/hip_runtime.h>

// B=8, C=128, H=96, W=96, D=4
// Single activation buffer "act": [b][d][h][w][kappa] bf16, channel axis stored
// in permuted kappa-order. sigma(kappa) = true channel. Scans run IN PLACE.
// Scan kernels: producer/consumer wave pairs, 4 chains per 512-thread block so
// every SIMD hosts 2 MFMA-active waves (a solo wave only sustains ~40cy/MFMA;
// two co-resident waves interleave issue slots).
//   producer wave: ff_h = bias + Wff @ input_h  -> f32 LDS ring (2 slots)
//   consumer wave: out_h = relu(ff_h + Wrec @ prev) -> pack -> global+regs

typedef short bf16x8 __attribute__((ext_vector_type(8)));
typedef float f32x4 __attribute__((ext_vector_type(4)));
typedef unsigned int uint4v __attribute__((ext_vector_type(4)));

__device__ __forceinline__ unsigned short f2bf(float f) {
  unsigned int u = __builtin_bit_cast(unsigned int, f);
  u = (u + 0x7FFFu + ((u >> 16) & 1u)) >> 16;
  return (unsigned short)u;
}
__device__ __forceinline__ float bf2f(unsigned short h) {
  unsigned int u = ((unsigned int)h) << 16;
  return __builtin_bit_cast(float, u);
}

// kappa = kt*32 + q*8 + j  ->  true channel c = kt*32 + (j>>2)*16 + q*4 + (j&3)
__device__ __forceinline__ int sigma_k(int kap) {
  int kt = kap >> 5, q = (kap >> 3) & 3, j = kap & 7;
  return kt * 32 + ((j >> 2) << 4) + q * 4 + (j & 3);
}

// ---------------- prep: cast weights to bf16 (columns kappa-permuted), sum biases
__global__ __launch_bounds__(256) void prep_kernel(
    const float* __restrict__ W1, const float* __restrict__ b1,
    const float* __restrict__ W2, const float* __restrict__ b2,
    const float* __restrict__ W4, const float* __restrict__ b4,
    const float* __restrict__ W5, const float* __restrict__ b5,
    unsigned short* __restrict__ Wb, float* __restrict__ bs12,
    float* __restrict__ bs45) {
  int gid = blockIdx.x * 256 + threadIdx.x;
  if (gid < 4 * 65536) {
    int m = gid >> 16;
    int r = gid & 65535;          // d*16384 + rho*128 + kappa
    int kap = r & 127;
    int c = sigma_k(kap);
    const float* src = (m == 0) ? W1 : (m == 1) ? W2 : (m == 2) ? W4 : W5;
    Wb[m * 65536 + r] = f2bf(src[(r >> 7) * 128 + c]);
  } else if (gid < 4 * 65536 + 512) {
    int r = gid - 4 * 65536;
    bs12[r] = b1[r] + b2[r];
  } else if (gid < 4 * 65536 + 1024) {
    int r = gid - 4 * 65536 - 512;
    bs45[r] = b4[r] + b5[r];
  }
}

// ---------------- transpose x -> act bf16 [b][d][h][w][kappa] ----------------
__global__ __launch_bounds__(256) void transpose_kernel(
    const float* __restrict__ x, unsigned short* __restrict__ act) {
  __shared__ unsigned short tile[128 * 208];
  int bid = blockIdx.x;
  int half = bid & 1;
  int rest = bid >> 1;
  int h = rest % 96;
  int b = rest / 96;
  int wd0 = half * 192;
  int tid = threadIdx.x;
#pragma unroll
  for (int it = 0; it < 12; ++it) {
    int cid = it * 256 + tid;
    int c = cid / 24;
    int k = cid % 24;
    const float* xp = x + ((size_t)(b * 128 + c) * 96 + h) * 384 + wd0 + k * 8;
    float4 v0 = *(const float4*)xp;
    float4 v1 = *(const float4*)(xp + 4);
    bf16x8 pk;
    pk[0] = (short)f2bf(v0.x); pk[1] = (short)f2bf(v0.y);
    pk[2] = (short)f2bf(v0.z); pk[3] = (short)f2bf(v0.w);
    pk[4] = (short)f2bf(v1.x); pk[5] = (short)f2bf(v1.y);
    pk[6] = (short)f2bf(v1.z); pk[7] = (short)f2bf(v1.w);
    int ks = k ^ ((c >> 3) & 7);
    *(bf16x8*)&tile[c * 208 + ks * 8] = pk;
  }
  __syncthreads();
#pragma unroll
  for (int it = 0; it < 12; ++it) {
    int sid = it * 256 + tid;
    int wdl = sid >> 4;
    int cc = sid & 15;              // kappa0 = cc*8
    int k = wdl >> 3, off = wdl & 7;
    int ktq = cc >> 2, qq = cc & 3;
    bf16x8 pk;
#pragma unroll
    for (int j = 0; j < 8; ++j) {
      int c = ktq * 32 + ((j >> 2) << 4) + qq * 4 + (j & 3);
      int ks = k ^ ((c >> 3) & 7);
      pk[j] = (short)tile[c * 208 + ks * 8 + off];
    }
    int wdg = wd0 + wdl;
    int d = wdg & 3, w = wdg >> 2;
    *(bf16x8*)(act + ((((size_t)(b * 4 + d) * 96 + h) * 96 + w) * 128 + cc * 8)) = pk;
  }
}

// ---------------- row scan: 4 chains/block, producer+consumer per chain ------
__global__ __launch_bounds__(512) void row_kernel(
    unsigned short* act, const unsigned short* __restrict__ Wb,
    const float* __restrict__ bs12) {
  __shared__ float slots[4][2][8][64][4];  // [chain][slot][mi][lane][4] = 64KB
  __shared__ int flags[4][64];             // [chain]: [0]=prod, [32]=cons
  int tid = threadIdx.x;
  int sc = tid >> 7;          // chain within block
  int ltid = tid & 127;
  int wave = ltid >> 6;
  int lane = ltid & 63;
  int q = lane >> 4;
  int n = lane & 15;
  int cid = blockIdx.x * 4 + sc;
  int wt = cid % 6;
  int bd = cid / 6;  // b*4+d
  int d = bd & 3;
  int w0 = wt * 16;
  volatile int* fprod = &flags[sc][0];
  volatile int* fcons = &flags[sc][32];
  if (ltid < 2) flags[sc][ltid * 32] = 0;
  __syncthreads();

  size_t bd9216 = (size_t)bd * 9216;
  size_t base = (bd9216 + (size_t)(w0 + n)) * 128 + q * 8;

  if (wave == 1) {
    // ---- ff producer: slot[h&1] = bias + W1 @ x_h ----
    const unsigned short* w1p = Wb + d * 16384;
    bf16x8 A1[8][4];
#pragma unroll
    for (int mi = 0; mi < 8; ++mi) {
      int c = mi * 16 + n;
#pragma unroll
      for (int kt = 0; kt < 4; ++kt)
        A1[mi][kt] = *(const bf16x8*)(w1p + c * 128 + kt * 32 + q * 8);
    }
    f32x4 bias[8];
#pragma unroll
    for (int mi = 0; mi < 8; ++mi)
#pragma unroll
      for (int r = 0; r < 4; ++r)
        bias[mi][r] = bs12[d * 128 + mi * 16 + q * 4 + r];
    const unsigned short* xrow = act + base;
    bf16x8 Bn[4], Bf[4];
    // invariant at loop entry h: Bn = x row h, Bf = x row h+1
#pragma unroll
    for (int kt = 0; kt < 4; ++kt) {
      Bn[kt] = *(const bf16x8*)(xrow + (size_t)1 * 12288 + kt * 32);
      Bf[kt] = *(const bf16x8*)(xrow + (size_t)2 * 12288 + kt * 32);
    }
#pragma unroll 1
    for (int h = 1; h <= 95; ++h) {
      while (h - *fcons > 2) __builtin_amdgcn_s_sleep(1);
      asm volatile("" ::: "memory");
      f32x4 acc[8];
#pragma unroll
      for (int mi = 0; mi < 8; ++mi)
        acc[mi] = __builtin_amdgcn_mfma_f32_16x16x32_bf16(A1[mi][0], Bn[0],
                                                          bias[mi], 0, 0, 0);
#pragma unroll
      for (int kt = 1; kt < 4; ++kt)
#pragma unroll
        for (int mi = 0; mi < 8; ++mi)
          acc[mi] = __builtin_amdgcn_mfma_f32_16x16x32_bf16(A1[mi][kt], Bn[kt],
                                                            acc[mi], 0, 0, 0);
      int hp = (h + 2 <= 95) ? h + 2 : 95;  // 2-deep rotation => distance 2
      const unsigned short* pf = xrow + (size_t)hp * 12288;
#pragma unroll
      for (int kt = 0; kt < 4; ++kt) {
        Bn[kt] = Bf[kt];
        Bf[kt] = *(const bf16x8*)(pf + kt * 32);
      }
      float* sp = &slots[sc][h & 1][0][lane][0];
#pragma unroll
      for (int mi = 0; mi < 8; ++mi)
        *(f32x4*)(sp + mi * 256) = acc[mi];
      asm volatile("s_waitcnt lgkmcnt(0)" ::: "memory");
      if (lane == 0) *fprod = h;
    }
  } else {
    // ---- rec consumer: act_h = relu(slot[h] + W2 @ prev) ----
    const unsigned short* w2p = Wb + 65536 + d * 16384;
    bf16x8 A2[8][4];
#pragma unroll
    for (int mi = 0; mi < 8; ++mi) {
      int c = mi * 16 + n;
#pragma unroll
      for (int kt = 0; kt < 4; ++kt)
        A2[mi][kt] = *(const bf16x8*)(w2p + c * 128 + kt * 32 + q * 8);
    }
    const unsigned short* xrow = act + base;
    unsigned short* outrow = act + base + 12288;
    bf16x8 Bp[4];
#pragma unroll
    for (int kt = 0; kt < 4; ++kt)
      Bp[kt] = *(const bf16x8*)(xrow + kt * 32);  // row0 seed (in place)
#pragma unroll 1
    for (int h = 1; h <= 95; ++h) {
      while (*fprod < h) __builtin_amdgcn_s_sleep(1);
      asm volatile("" ::: "memory");
      const float* sp = &slots[sc][h & 1][0][lane][0];
      f32x4 acc[8];
#pragma unroll
      for (int mi = 0; mi < 8; ++mi)
        acc[mi] = *(const f32x4*)(sp + mi * 256);
#pragma unroll
      for (int kt = 0; kt < 4; ++kt)
#pragma unroll
        for (int mi = 0; mi < 8; ++mi)
          acc[mi] = __builtin_amdgcn_mfma_f32_16x16x32_bf16(A2[mi][kt], Bp[kt],
                                                            acc[mi], 0, 0, 0);
#pragma unroll
      for (int kt = 0; kt < 4; ++kt) {
        unsigned int u0, u1, u2, u3;
        float a0 = fmaxf(acc[2 * kt][0], 0.f);
        float a1 = fmaxf(acc[2 * kt][1], 0.f);
        float a2 = fmaxf(acc[2 * kt][2], 0.f);
        float a3 = fmaxf(acc[2 * kt][3], 0.f);
        float c0 = fmaxf(acc[2 * kt + 1][0], 0.f);
        float c1 = fmaxf(acc[2 * kt + 1][1], 0.f);
        float c2 = fmaxf(acc[2 * kt + 1][2], 0.f);
        float c3 = fmaxf(acc[2 * kt + 1][3], 0.f);
        asm("v_cvt_pk_bf16_f32 %0, %1, %2" : "=v"(u0) : "v"(a0), "v"(a1));
        asm("v_cvt_pk_bf16_f32 %0, %1, %2" : "=v"(u1) : "v"(a2), "v"(a3));
        asm("v_cvt_pk_bf16_f32 %0, %1, %2" : "=v"(u2) : "v"(c0), "v"(c1));
        asm("v_cvt_pk_bf16_f32 %0, %1, %2" : "=v"(u3) : "v"(c2), "v"(c3));
        uint4v uu;
        uu[0] = u0; uu[1] = u1; uu[2] = u2; uu[3] = u3;
        Bp[kt] = __builtin_bit_cast(bf16x8, uu);
        *(bf16x8*)(outrow + kt * 32) = Bp[kt];
      }
      outrow += 12288;
      asm volatile("" ::: "memory");
      if (lane == 0) *fcons = h;
    }
  }
}

// ---------------- col scan: 4 chains/block, producer+consumer, in place ------
__global__ __launch_bounds__(512) void col_kernel(
    unsigned short* act, const unsigned short* __restrict__ Wb,
    const float* __restrict__ bs45) {
  __shared__ float slots[4][2][8][64][4];
  __shared__ int flags[4][64];
  int tid = threadIdx.x;
  int sc = tid >> 7;
  int ltid = tid & 127;
  int wave = ltid >> 6;
  int lane = ltid & 63;
  int q = lane >> 4;
  int n = lane & 15;
  int cid = blockIdx.x * 4 + sc;
  int ht = cid % 6;
  int bd = cid / 6;
  int d = bd & 3;
  int h0 = ht * 16;
  volatile int* fprod = &flags[sc][0];
  volatile int* fcons = &flags[sc][32];
  if (ltid < 2) flags[sc][ltid * 32] = 0;
  __syncthreads();

  size_t bd9216 = (size_t)bd * 9216;
  size_t base = (bd9216 + (size_t)(h0 + n) * 96) * 128 + q * 8;

  if (wave == 1) {
    // ---- ff producer: slot[w&1] = bias + W4 @ hs_w ----
    const unsigned short* w4p = Wb + 2 * 65536 + d * 16384;
    bf16x8 A1[8][4];
#pragma unroll
    for (int mi = 0; mi < 8; ++mi) {
      int c = mi * 16 + n;
#pragma unroll
      for (int kt = 0; kt < 4; ++kt)
        A1[mi][kt] = *(const bf16x8*)(w4p + c * 128 + kt * 32 + q * 8);
    }
    f32x4 bias[8];
#pragma unroll
    for (int mi = 0; mi < 8; ++mi)
#pragma unroll
      for (int r = 0; r < 4; ++r)
        bias[mi][r] = bs45[d * 128 + mi * 16 + q * 4 + r];
    const unsigned short* ccol = act + base;
    bf16x8 Bn[4], Bf[4];
    // invariant at loop entry w: Bn = hs col w, Bf = hs col w+1
#pragma unroll
    for (int kt = 0; kt < 4; ++kt) {
      Bn[kt] = *(const bf16x8*)(ccol + (size_t)1 * 128 + kt * 32);
      Bf[kt] = *(const bf16x8*)(ccol + (size_t)2 * 128 + kt * 32);
    }
#pragma unroll 1
    for (int w = 1; w <= 95; ++w) {
      while (w - *fcons > 2) __builtin_amdgcn_s_sleep(1);
      asm volatile("" ::: "memory");
      f32x4 acc[8];
#pragma unroll
      for (int mi = 0; mi < 8; ++mi)
        acc[mi] = __builtin_amdgcn_mfma_f32_16x16x32_bf16(A1[mi][0], Bn[0],
                                                          bias[mi], 0, 0, 0);
#pragma unroll
      for (int kt = 1; kt < 4; ++kt)
#pragma unroll
        for (int mi = 0; mi < 8; ++mi)
          acc[mi] = __builtin_amdgcn_mfma_f32_16x16x32_bf16(A1[mi][kt], Bn[kt],
                                                            acc[mi], 0, 0, 0);
      int wp = (w + 2 <= 95) ? w + 2 : 95;  // 2-deep rotation => distance 2
      const unsigned short* pf = ccol + (size_t)wp * 128;
#pragma unroll
      for (int kt = 0; kt < 4; ++kt) {
        Bn[kt] = Bf[kt];
        Bf[kt] = *(const bf16x8*)(pf + kt * 32);
      }
      float* sp = &slots[sc][w & 1][0][lane][0];
#pragma unroll
      for (int mi = 0; mi < 8; ++mi)
        *(f32x4*)(sp + mi * 256) = acc[mi];
      asm volatile("s_waitcnt lgkmcnt(0)" ::: "memory");
      if (lane == 0) *fprod = w;
    }
  } else {
    // ---- rec consumer: hid_w = relu(slot[w] + W5 @ prev) ----
    const unsigned short* w5p = Wb + 3 * 65536 + d * 16384;
    bf16x8 A2[8][4];
#pragma unroll
    for (int mi = 0; mi < 8; ++mi) {
      int c = mi * 16 + n;
#pragma unroll
      for (int kt = 0; kt < 4; ++kt)
        A2[mi][kt] = *(const bf16x8*)(w5p + c * 128 + kt * 32 + q * 8);
    }
    const unsigned short* ccol = act + base;
    unsigned short* outrow = act + base;
    bf16x8 Bp[4];
#pragma unroll
    for (int kt = 0; kt < 4; ++kt) {
      bf16x8 v = *(const bf16x8*)(ccol + kt * 32);
#pragma unroll
      for (int j = 0; j < 8; ++j) {
        unsigned short uv = (unsigned short)v[j];
        if (uv & 0x8000u) v[j] = 0;  // bf16 relu
      }
      Bp[kt] = v;
      *(bf16x8*)(outrow + kt * 32) = v;  // hid col0 = relu(hs col0), in place
    }
    outrow += 128;
#pragma unroll 1
    for (int w = 1; w <= 95; ++w) {
      while (*fprod < w) __builtin_amdgcn_s_sleep(1);
      asm volatile("" ::: "memory");
      const float* sp = &slots[sc][w & 1][0][lane][0];
      f32x4 acc[8];
#pragma unroll
      for (int mi = 0; mi < 8; ++mi)
        acc[mi] = *(const f32x4*)(sp + mi * 256);
#pragma unroll
      for (int kt = 0; kt < 4; ++kt)
#pragma unroll
        for (int mi = 0; mi < 8; ++mi)
          acc[mi] = __builtin_amdgcn_mfma_f32_16x16x32_bf16(A2[mi][kt], Bp[kt],
                                                            acc[mi], 0, 0, 0);
#pragma unroll
      for (int kt = 0; kt < 4; ++kt) {
        unsigned int u0, u1, u2, u3;
        float a0 = fmaxf(acc[2 * kt][0], 0.f);
        float a1 = fmaxf(acc[2 * kt][1], 0.f);
        float a2 = fmaxf(acc[2 * kt][2], 0.f);
        float a3 = fmaxf(acc[2 * kt][3], 0.f);
        float c0 = fmaxf(acc[2 * kt + 1][0], 0.f);
        float c1 = fmaxf(acc[2 * kt + 1][1], 0.f);
        float c2 = fmaxf(acc[2 * kt + 1][2], 0.f);
        float c3 = fmaxf(acc[2 * kt + 1][3], 0.f);
        asm("v_cvt_pk_bf16_f32 %0, %1, %2" : "=v"(u0) : "v"(a0), "v"(a1));
        asm("v_cvt_pk_bf16_f32 %0, %1, %2" : "=v"(u1) : "v"(a2), "v"(a3));
        asm("v_cvt_pk_bf16_f32 %0, %1, %2" : "=v"(u2) : "v"(c0), "v"(c1));
        asm("v_cvt_pk_bf16_f32 %0, %1, %2" : "=v"(u3) : "v"(c2), "v"(c3));
        uint4v uu;
        uu[0] = u0; uu[1] = u1; uu[2] = u2; uu[3] = u3;
        Bp[kt] = __builtin_bit_cast(bf16x8, uu);
        *(bf16x8*)(outrow + kt * 32) = Bp[kt];
      }
      outrow += 128;
      asm volatile("" ::: "memory");
      if (lane == 0) *fcons = w;
    }
  }
}

// ---------------- out = x + unpermute(act) ----------------
__global__ __launch_bounds__(256) void out_kernel(
    const float* __restrict__ x, const unsigned short* __restrict__ act,
    float* __restrict__ out) {
  __shared__ unsigned short tile[128 * 208];
  int bid = blockIdx.x;
  int half = bid & 1;
  int rest = bid >> 1;
  int h = rest % 96;
  int b = rest / 96;
  int wd0 = half * 192;
  int tid = threadIdx.x;
#pragma unroll
  for (int it = 0; it < 12; ++it) {
    int gid = it * 256 + tid;
    int wdl = gid >> 4;
    int cc = gid & 15;              // kappa0 = cc*8
    int wdg = wd0 + wdl;
    int d = wdg & 3, w = wdg >> 2;
    bf16x8 v = *(const bf16x8*)(
        act + ((((size_t)(b * 4 + d) * 96 + h) * 96 + w) * 128 + cc * 8));
    int k = wdl >> 3, off = wdl & 7;
    int ktq = cc >> 2, qq = cc & 3;
#pragma unroll
    for (int j = 0; j < 8; ++j) {
      int c = ktq * 32 + ((j >> 2) << 4) + qq * 4 + (j & 3);
      int ks = k ^ ((c >> 3) & 7);
      tile[c * 208 + ks * 8 + off] = (unsigned short)v[j];
    }
  }
  __syncthreads();
#pragma unroll
  for (int it = 0; it < 12; ++it) {
    int sid = it * 256 + tid;
    int c = sid / 24;
    int k = sid % 24;
    int ks = k ^ ((c >> 3) & 7);
    bf16x8 pk = *(const bf16x8*)&tile[c * 208 + ks * 8];
    size_t o = ((size_t)(b * 128 + c) * 96 + h) * 384 + wd0 + k * 8;
    float4 a0 = *(const float4*)(x + o);
    float4 a1 = *(const float4*)(x + o + 4);
    float4 r0, r1;
    r0.x = a0.x + bf2f((unsigned short)pk[0]);
    r0.y = a0.y + bf2f((unsigned short)pk[1]);
    r0.z = a0.z + bf2f((unsigned short)pk[2]);
    r0.w = a0.w + bf2f((unsigned short)pk[3]);
    r1.x = a1.x + bf2f((unsigned short)pk[4]);
    r1.y = a1.y + bf2f((unsigned short)pk[5]);
    r1.z = a1.z + bf2f((unsigned short)pk[6]);
    r1.w = a1.w + bf2f((unsigned short)pk[7]);
    *(float4*)(out + o) = r0;
    *(float4*)(out + o + 4) = r1;
  }
}

extern "C" void kernel_launch(void* const* d_in, const int* in_sizes, int n_in,
                              void* d_out, int out_size, void* d_ws,
                              size_t ws_size, hipStream_t stream) {
  (void)in_sizes; (void)n_in; (void)out_size; (void)ws_size;
  const float* x  = (const float*)d_in[0];
  const float* W1 = (const float*)d_in[1];
  const float* b1 = (const float*)d_in[2];
  const float* W2 = (const float*)d_in[3];
  const float* b2 = (const float*)d_in[4];
  const float* W4 = (const float*)d_in[5];
  const float* b4 = (const float*)d_in[6];
  const float* W5 = (const float*)d_in[7];
  const float* b5 = (const float*)d_in[8];
  float* out = (float*)d_out;

  char* ws = (char*)d_ws;
  unsigned short* Wb  = (unsigned short*)(ws);            // 524288 B
  float* bs12         = (float*)(ws + 524288);            // 2048 B
  float* bs45         = (float*)(ws + 526336);            // 2048 B
  unsigned short* act = (unsigned short*)(ws + 528384);   // 75497472 B

  prep_kernel<<<(4 * 65536 + 1024 + 255) / 256, 256, 0, stream>>>(
      W1, b1, W2, b2, W4, b4, W5, b5, Wb, bs12, bs45);
  transpose_kernel<<<8 * 96 * 2, 256, 0, stream>>>(x, act);
  row_kernel<<<48, 512, 0, stream>>>(act, Wb, bs12);
  col_kernel<<<48, 512, 0, stream>>>(act, Wb, bs45);
  out_kernel<<<8 * 96 * 2, 256, 0, stream>>>(x, act, out);
}